// Round 9
// baseline (52.260 us; speedup 1.0000x reference)
//
#include <hip/hip_runtime.h>

// FractalEmbedding: out[b,l,d] = scale * sum_f feats(token)[f] * W[d,f]
// feats = 8-step Julia iteration on c_table[token], interleaved (zr,zi).
//
// B=8, L=8192 -> 65536 tokens; D=1024; 16 features. Output 268 MB f32.
// Plateau analysis (R5 50.3 / R7 52.1 despite 2x occupancy + 2x issue
// differences): both drain their stores every iteration (store-data reg
// reuse under unroll 1) -> in-flight store bytes/CU ~16-32 KB, vs the fill
// kernel's unbounded queue at 7.0 TB/s. Lever = store window DEPTH.
// This version:
//  - 2 dims/thread (wp = 32 VGPR), BLOCK=512, __launch_bounds__(512,4):
//    128-VGPR tier with ~18 regs of slack for the unroller.
//  - one-token body, #pragma unroll 4: distinct feats/acc/store regs per
//    body -> 4+ stores in flight per wave (vmcnt(3+) instead of drain-0).
//  - TPB=128, GRID=512: exact 2 blocks/CU residency, no tail.
//  - unchanged: LDS feats dedup (bit-identical Julia, once per block),
//    packed floatx2 dot (per-dim chain order = reference k ascending),
//    plain stores, zero global loads in the main loop.

#define STEPS 8
#define NFEAT (2 * STEPS)
#define EMBED 1024
#define NTOK (8 * 8192)
#define TPB 128                // tokens per block
#define BLOCK 512
#define GRID (NTOK / TPB)      // 512

typedef float floatx2 __attribute__((ext_vector_type(2)));

__global__ __launch_bounds__(BLOCK, 4) void FractalEmbedding_30365418782757_kernel(
    const int* __restrict__ tok,
    const float* __restrict__ ctab,   // (V, 2)
    const float* __restrict__ W,      // (1024, 16) row-major
    const float* __restrict__ scale_p,
    float* __restrict__ out)          // (NTOK, 1024)
{
    const int t = threadIdx.x;  // thread t -> output dims 2t, 2t+1
    const float s = *scale_p;

    __shared__ float4 fs4[TPB * 4];   // 8 KB: per-token features

    const int base = blockIdx.x * TPB;

    // One-time: threads 0..127 compute one token's Julia features each.
    if (t < TPB) {
        const int id = tok[base + t];
        const float2 c = reinterpret_cast<const float2*>(ctab)[id];
        float loc[NFEAT];
        float zr = 0.0f, zi = 0.0f;
#pragma unroll
        for (int st = 0; st < STEPS; ++st) {
            float nzr = zr * zr - zi * zi + c.x;
            float nzi = 2.0f * zr * zi + c.y;
            zr = nzr; zi = nzi;
            loc[2 * st]     = zr;
            loc[2 * st + 1] = zi;
        }
#pragma unroll
        for (int q = 0; q < 4; ++q)
            fs4[t * 4 + q] = reinterpret_cast<const float4*>(loc)[q];
    }

    // W packed across this thread's dim pair: wp[k] = { W[2t][k], W[2t+1][k] } * s
    floatx2 wp[NFEAT];
    {
        const float4* r0 = reinterpret_cast<const float4*>(W + (size_t)(2 * t)     * NFEAT);
        const float4* r1 = reinterpret_cast<const float4*>(W + (size_t)(2 * t + 1) * NFEAT);
#pragma unroll
        for (int q = 0; q < 4; ++q) {
            float4 a = r0[q];
            float4 b = r1[q];
            wp[4 * q + 0] = floatx2{a.x * s, b.x * s};
            wp[4 * q + 1] = floatx2{a.y * s, b.y * s};
            wp[4 * q + 2] = floatx2{a.z * s, b.z * s};
            wp[4 * q + 3] = floatx2{a.w * s, b.w * s};
        }
    }

    __syncthreads();

    float2* out2 = reinterpret_cast<float2*>(out);

    // Main loop: one token per body, unroll 4 -> distinct register sets per
    // body, stores stay in flight across bodies. 4 broadcast ds_read_b128 +
    // 16 v_pk_fma + 1 dwordx2 store per token. No global loads.
#pragma unroll 4
    for (int i = 0; i < TPB; ++i) {
        const float4 g0 = fs4[i * 4 + 0];
        const float4 g1 = fs4[i * 4 + 1];
        const float4 g2 = fs4[i * 4 + 2];
        const float4 g3 = fs4[i * 4 + 3];

        // Per-dim chain order is exactly k = 0..15 (reference order).
        floatx2 acc = {0.f, 0.f};
        acc += floatx2{g0.x, g0.x} * wp[0];
        acc += floatx2{g0.y, g0.y} * wp[1];
        acc += floatx2{g0.z, g0.z} * wp[2];
        acc += floatx2{g0.w, g0.w} * wp[3];
        acc += floatx2{g1.x, g1.x} * wp[4];
        acc += floatx2{g1.y, g1.y} * wp[5];
        acc += floatx2{g1.z, g1.z} * wp[6];
        acc += floatx2{g1.w, g1.w} * wp[7];
        acc += floatx2{g2.x, g2.x} * wp[8];
        acc += floatx2{g2.y, g2.y} * wp[9];
        acc += floatx2{g2.z, g2.z} * wp[10];
        acc += floatx2{g2.w, g2.w} * wp[11];
        acc += floatx2{g3.x, g3.x} * wp[12];
        acc += floatx2{g3.y, g3.y} * wp[13];
        acc += floatx2{g3.z, g3.z} * wp[14];
        acc += floatx2{g3.w, g3.w} * wp[15];

        float2 o; o.x = acc.x; o.y = acc.y;
        out2[(size_t)(base + i) * (EMBED / 2) + t] = o;
    }
}

extern "C" void kernel_launch(void* const* d_in, const int* in_sizes, int n_in,
                              void* d_out, int out_size, void* d_ws, size_t ws_size,
                              hipStream_t stream) {
    const int*   tok   = (const int*)d_in[0];
    const float* ctab  = (const float*)d_in[1];
    const float* W     = (const float*)d_in[2];
    const float* scale = (const float*)d_in[3];
    float*       out   = (float*)d_out;

    FractalEmbedding_30365418782757_kernel<<<GRID, BLOCK, 0, stream>>>(tok, ctab, W, scale, out);
}

// Round 10
// 50.865 us; speedup vs baseline: 1.0274x; 1.0274x over previous
//
#include <hip/hip_runtime.h>

// FractalEmbedding: out[b,l,d] = scale * sum_f feats(token)[f] * W[d,f]
// feats = 8-step Julia iteration on c_table[token], interleaved (zr,zi).
//
// B=8, L=8192 -> 65536 tokens; D=1024; 16 features. Output 268 MB f32.
// FINAL (revert to best = R5, 50.3us = 5.34 TB/s effective write BW).
// Plateau evidence: five structurally distinct kernels (issue count x2.4,
// occupancy x2, store width x2, store depth x4, zero in-loop global loads)
// all land 50.3-57.9us; compute/store overlap is empirically additive and
// every attempt to break it failed. Issue floor ~10us chip-wide + 38us
// store drain ~= 45-46us model floor; 50.3 measured.
// Structure:
//  - Julia dedup: threads 0..63 compute all 64 tokens' feats ONCE into
//    4 KB LDS (bit-identical); main loop reads via broadcast ds_read_b128.
//  - packed-FP32 dot: accumulators packed across independent output dims
//    (floatx2) -> v_pk_fma_f32; per-dim chain order = reference k ascending.
//  - zero global loads in main loop; plain float4 stores.
//  - GRID=1024, BLOCK=256, 4 dims/thread: exact residency, no tail.

#define STEPS 8
#define NFEAT (2 * STEPS)
#define EMBED 1024
#define NTOK (8 * 8192)
#define TPB 64                 // tokens per block
#define BLOCK 256
#define GRID (NTOK / TPB)      // 1024

typedef float floatx2 __attribute__((ext_vector_type(2)));

__global__ __launch_bounds__(BLOCK, 4) void FractalEmbedding_30365418782757_kernel(
    const int* __restrict__ tok,
    const float* __restrict__ ctab,   // (V, 2)
    const float* __restrict__ W,      // (1024, 16) row-major
    const float* __restrict__ scale_p,
    float* __restrict__ out)          // (NTOK, 1024)
{
    const int t = threadIdx.x;  // thread t -> output dims 4t .. 4t+3
    const float s = *scale_p;

    __shared__ float fs[TPB][NFEAT];   // 4 KB: per-token features

    const int base = blockIdx.x * TPB;

    // One-time: threads 0..63 compute one token's Julia features each.
    if (t < TPB) {
        const int id = tok[base + t];
        const float2 c = reinterpret_cast<const float2*>(ctab)[id];
        float loc[NFEAT];
        float zr = 0.0f, zi = 0.0f;
#pragma unroll
        for (int st = 0; st < STEPS; ++st) {
            float nzr = zr * zr - zi * zi + c.x;
            float nzi = 2.0f * zr * zi + c.y;
            zr = nzr; zi = nzi;
            loc[2 * st]     = zr;
            loc[2 * st + 1] = zi;
        }
        float4* dst = reinterpret_cast<float4*>(fs[t]);
#pragma unroll
        for (int q = 0; q < 4; ++q)
            dst[q] = reinterpret_cast<const float4*>(loc)[q];
    }

    // W packed across dim-pairs: wp[j][k] = { W[4t+2j][k], W[4t+2j+1][k] } * s
    floatx2 wp[2][NFEAT];
#pragma unroll
    for (int j = 0; j < 2; ++j) {
        const float4* r0 = reinterpret_cast<const float4*>(W + (size_t)(4 * t + 2 * j)     * NFEAT);
        const float4* r1 = reinterpret_cast<const float4*>(W + (size_t)(4 * t + 2 * j + 1) * NFEAT);
#pragma unroll
        for (int q = 0; q < 4; ++q) {
            float4 a = r0[q];
            float4 b = r1[q];
            wp[j][4 * q + 0] = floatx2{a.x * s, b.x * s};
            wp[j][4 * q + 1] = floatx2{a.y * s, b.y * s};
            wp[j][4 * q + 2] = floatx2{a.z * s, b.z * s};
            wp[j][4 * q + 3] = floatx2{a.w * s, b.w * s};
        }
    }

    __syncthreads();

    // Main loop: LDS broadcast reads + packed FMA + stores. No global loads.
#pragma unroll 1
    for (int i = 0; i < TPB; i += 2) {
        // Both tokens' 16 feats via broadcast ds_read_b128 (conflict-free).
        float g0[NFEAT], g1[NFEAT];
        const float4* p0 = reinterpret_cast<const float4*>(fs[i]);
        const float4* p1 = reinterpret_cast<const float4*>(fs[i + 1]);
#pragma unroll
        for (int q = 0; q < 4; ++q) {
            float4 v0 = p0[q];
            g0[4 * q + 0] = v0.x; g0[4 * q + 1] = v0.y;
            g0[4 * q + 2] = v0.z; g0[4 * q + 3] = v0.w;
            float4 v1 = p1[q];
            g1[4 * q + 0] = v1.x; g1[4 * q + 1] = v1.y;
            g1[4 * q + 2] = v1.z; g1[4 * q + 3] = v1.w;
        }

        // Packed dot: per-dim chain order is exactly k = 0..15 (reference).
        floatx2 a00 = {0.f, 0.f}, a01 = {0.f, 0.f};   // token0 dims {0,1},{2,3}
        floatx2 a10 = {0.f, 0.f}, a11 = {0.f, 0.f};   // token1
#pragma unroll
        for (int k = 0; k < NFEAT; ++k) {
            floatx2 fb0 = {g0[k], g0[k]};
            floatx2 fb1 = {g1[k], g1[k]};
            a00 += fb0 * wp[0][k];
            a01 += fb0 * wp[1][k];
            a10 += fb1 * wp[0][k];
            a11 += fb1 * wp[1][k];
        }

        float4 o0; o0.x = a00.x; o0.y = a00.y; o0.z = a01.x; o0.w = a01.y;
        float4 o1; o1.x = a10.x; o1.y = a10.y; o1.z = a11.x; o1.w = a11.y;
        reinterpret_cast<float4*>(out + (size_t)(base + i)     * EMBED)[t] = o0;
        reinterpret_cast<float4*>(out + (size_t)(base + i + 1) * EMBED)[t] = o1;
    }
}

extern "C" void kernel_launch(void* const* d_in, const int* in_sizes, int n_in,
                              void* d_out, int out_size, void* d_ws, size_t ws_size,
                              hipStream_t stream) {
    const int*   tok   = (const int*)d_in[0];
    const float* ctab  = (const float*)d_in[1];
    const float* W     = (const float*)d_in[2];
    const float* scale = (const float*)d_in[3];
    float*       out   = (float*)d_out;

    FractalEmbedding_30365418782757_kernel<<<GRID, BLOCK, 0, stream>>>(tok, ctab, W, scale, out);
}